// Round 18
// baseline (4227.039 us; speedup 1.0000x reference)
//
#include <hip/hip_runtime.h>
#include <hip/hip_bf16.h>

// Problem: out[M=4096][N=16384] = x[M][K=4096] @ (W[N][K] * scale[N/128][K/128])^T + bias[N]
#define M_DIM 4096
#define N_DIM 16384
#define K_DIM 4096

typedef __bf16 bf16x8 __attribute__((ext_vector_type(8)));
typedef float f32x4 __attribute__((ext_vector_type(4)));

__device__ __forceinline__ void gload16(const void* g, void* l) {
    __builtin_amdgcn_global_load_lds((__attribute__((address_space(1))) void*)g,
                                     (__attribute__((address_space(3))) void*)l, 16, 0, 0);
}

// ---------- fused prepass: x fp32->bf16  +  W fp32*scale->bf16 (verified) ----
__global__ __launch_bounds__(256) void prep_kernel(const float* __restrict__ x,
                                                   const float* __restrict__ wgt,
                                                   const float* __restrict__ scale,
                                                   __hip_bfloat16* __restrict__ xbf,
                                                   __hip_bfloat16* __restrict__ wbf) {
    int b = blockIdx.x;
    if (b < 2048) {
        const int ng = M_DIM * K_DIM / 8;
        int i = b * 256 + threadIdx.x;
        for (; i < ng; i += 2048 * 256) {
            const float4* p = (const float4*)(x + (size_t)i * 8);
            float4 v0 = p[0];
            float4 v1 = p[1];
            bf16x8 r;
            r[0] = (__bf16)v0.x; r[1] = (__bf16)v0.y; r[2] = (__bf16)v0.z; r[3] = (__bf16)v0.w;
            r[4] = (__bf16)v1.x; r[5] = (__bf16)v1.y; r[6] = (__bf16)v1.z; r[7] = (__bf16)v1.w;
            *(bf16x8*)(xbf + (size_t)i * 8) = r;
        }
    } else {
        const int ng = N_DIM * (K_DIM / 8);
        int i = (b - 2048) * 256 + threadIdx.x;
        for (; i < ng; i += 4096 * 256) {
            int row = i >> 9;
            int cg  = i & 511;
            float s = scale[(row >> 7) * (K_DIM / 128) + (cg >> 4)];
            const float4* p = (const float4*)(wgt + (size_t)i * 8);
            float4 v0 = p[0];
            float4 v1 = p[1];
            bf16x8 r;
            r[0] = (__bf16)(v0.x * s); r[1] = (__bf16)(v0.y * s);
            r[2] = (__bf16)(v0.z * s); r[3] = (__bf16)(v0.w * s);
            r[4] = (__bf16)(v1.x * s); r[5] = (__bf16)(v1.y * s);
            r[6] = (__bf16)(v1.z * s); r[7] = (__bf16)(v1.w * s);
            *(bf16x8*)(wbf + (size_t)i * 8) = r;
        }
    }
}

// ---------- main GEMM: 256x256 tile, BK=32, 4 waves x 128x128, 2 blocks/CU --
// Geometry change (not schedule): per-CU LDS-read traffic drops 192->128 b128
// per K=64 (-33%: per-wave 128x128 output shares each fragment across 2x the
// MFMAs), and 64 KiB LDS -> 2 independent blocks/CU whose barriers interleave
// (m97/m114 cross-block overlap) -- replacing the intra-block pipelining that
// 8 schedule variants failed to achieve. Grid stays 1024 (no r12 L2 thrash).
// LDS: 256 rows x 4 slots(16B) per buffer; cell (r,s) holds k-octet
// s ^ ((r>>1)&3) (XOR swizzle; r13 measured the equivalent 8-lane bank-group
// pattern at ZERO SQ_LDS_BANK_CONFLICT -- multi-row same-bank b128 bursts are
// bandwidth, not conflicts). Staged per rule #21: linear LDS dest,
// pre-swizzled global col ((l&3)^((l>>3)&3))*8 (invariant across j,w: row>>1
// low bits = (l>>3)&3). Free-zone per K-step (r12 race-proven):
//   vmcnt(8|0); BAR; [16 ds_read + 64 MFMA, compiler-scheduled];
//   lgkm0; BAR; stage(kt+2)->buf[cur] (8 gloads).
// vmcnt(8): queue = stage(kt)+stage(kt+1) (8 each, in-order) -> retires
// stage(kt) exactly; stage slack = 1 full K-step + other block's work.
template <int WN, bool ST>
__device__ __forceinline__ void ktile(const bf16x8* __restrict__ pa,
                                      const bf16x8* __restrict__ pb,
                                      char* lA, char* lB,
                                      const __hip_bfloat16* __restrict__ gA2,
                                      const __hip_bfloat16* __restrict__ gB2,
                                      f32x4 (&acc)[8][8],
                                      int arow, int brow, int srow) {
    const size_t K = K_DIM;
    if (WN == 0) asm volatile("s_waitcnt vmcnt(0)" ::: "memory");
    else         asm volatile("s_waitcnt vmcnt(8)" ::: "memory");
    __builtin_amdgcn_s_barrier();

    // free zone: compiler schedules reads <-> MFMAs
    bf16x8 a[8], b[8];
    #pragma unroll
    for (int mi = 0; mi < 8; ++mi)
        a[mi] = pa[arow + mi * 64];
    #pragma unroll
    for (int ni = 0; ni < 8; ++ni)
        b[ni] = pb[brow + ni * 64];
    __builtin_amdgcn_s_setprio(1);
    #pragma unroll
    for (int mi = 0; mi < 8; ++mi)
        #pragma unroll
        for (int ni = 0; ni < 8; ++ni)
            acc[mi][ni] = __builtin_amdgcn_mfma_f32_16x16x32_bf16(
                a[mi], b[ni], acc[mi][ni], 0, 0, 0);
    __builtin_amdgcn_s_setprio(0);

    asm volatile("s_waitcnt lgkmcnt(0)" ::: "memory");
    __builtin_amdgcn_s_barrier();
    if (ST) {
        #pragma unroll
        for (int j = 0; j < 4; ++j) {
            gload16(gA2 + (size_t)(j * 64 + srow) * K, lA + j * 4096);
            gload16(gB2 + (size_t)(j * 64 + srow) * K, lB + j * 4096);
        }
    }
}

__global__ __launch_bounds__(256, 2)
void gemm_bf16_kernel(const __hip_bfloat16* __restrict__ A,   // [M][K] bf16
                      const __hip_bfloat16* __restrict__ Bw,  // [N][K] bf16
                      const float* __restrict__ bias,
                      float* __restrict__ C) {                // [M][N] fp32
    constexpr int Mtiles = M_DIM / 256;            // 16
    constexpr int Ntiles = N_DIM / 256;            // 64
    constexpr int nwg = Mtiles * Ntiles;           // 1024 (div by 8)

    int bid = blockIdx.x;
    int swz = (bid & 7) * (nwg >> 3) + (bid >> 3);   // bijective XCD swizzle
    int bm = swz % Mtiles;
    int bn = swz / Mtiles;

    __shared__ bf16x8 sA[2][1024];   // 256 rows x 4 slots x 16B = 16 KiB each
    __shared__ bf16x8 sB[2][1024];   // total 64 KiB -> 2 blocks/CU

    const int t = threadIdx.x;
    const int l = t & 63;
    const int w = t >> 6;        // wave 0..3
    const int wm = w >> 1;       // 0..1  (M half)
    const int wn = w & 1;        // 0..1  (N half)

    const int lr = l & 15;
    const int lk = l >> 4;       // k-octet 0..3
    const int sr = lk ^ ((lr >> 1) & 3);   // swizzled read slot

    // staging (rule #21): linear LDS dest, pre-swizzled global source col.
    const int srow = w * 16 + (l >> 2);            // + j*64 per gload
    const int scol = ((l & 3) ^ ((l >> 3) & 3)) << 3;

    const size_t K = K_DIM;
    const __hip_bfloat16* aB = A  + (size_t)(bm * 256) * K + scol;
    const __hip_bfloat16* bB = Bw + (size_t)(bn * 256) * K + scol;

    f32x4 acc[8][8] = {};

    const int arow = (wm * 128 + lr) * 4 + sr;   // + mi*64 slots
    const int brow = (wn * 128 + lr) * 4 + sr;   // + ni*64 slots

    char* A0b = (char*)&sA[0][0] + w * 1024;
    char* B0b = (char*)&sB[0][0] + w * 1024;
    char* A1b = (char*)&sA[1][0] + w * 1024;
    char* B1b = (char*)&sB[1][0] + w * 1024;
    const bf16x8* pa0 = &sA[0][0];
    const bf16x8* pb0 = &sB[0][0];
    const bf16x8* pa1 = &sA[1][0];
    const bf16x8* pb1 = &sB[1][0];

#define STAGE8(lA, lB, gA, gB)                                                  \
    do {                                                                        \
        _Pragma("unroll")                                                       \
        for (int j = 0; j < 4; ++j) {                                           \
            gload16((gA) + (size_t)(j * 64 + srow) * K, (lA) + j * 4096);       \
            gload16((gB) + (size_t)(j * 64 + srow) * K, (lB) + j * 4096);       \
        }                                                                       \
    } while (0)

    // prologue: stage step0 -> buf0, step1 -> buf1 (16 gloads in flight)
    STAGE8(A0b, B0b, aB, bB);
    STAGE8(A1b, B1b, aB + 32, bB + 32);

    #pragma unroll 1
    for (int p = 0; p < 63; ++p) {
        const int kt = 2 * p;
        ktile<8, true>(pa0, pb0, A0b, B0b,
                       aB + (size_t)(kt + 2) * 32, bB + (size_t)(kt + 2) * 32,
                       acc, arow, brow, srow);
        ktile<8, true>(pa1, pb1, A1b, B1b,
                       aB + (size_t)(kt + 3) * 32, bB + (size_t)(kt + 3) * 32,
                       acc, arow, brow, srow);
    }
    // steps 126, 127: no further staging
    ktile<8, false>(pa0, pb0, A0b, B0b, aB, bB, acc, arow, brow, srow);
    ktile<0, false>(pa1, pb1, A1b, B1b, aB, bB, acc, arow, brow, srow);
#undef STAGE8

    // epilogue: C/D layout col=lane&15, row=(lane>>4)*4+reg  [m89-verified]
    const int crow0 = bm * 256 + wm * 128;
    const int ccol0 = bn * 256 + wn * 128;
    #pragma unroll
    for (int ni = 0; ni < 8; ++ni) {
        int col = ccol0 + ni * 16 + lr;
        float bv = bias[col];
        #pragma unroll
        for (int mi = 0; mi < 8; ++mi) {
            int rbase = crow0 + mi * 16 + lk * 4;
            #pragma unroll
            for (int j = 0; j < 4; ++j) {
                C[(size_t)(rbase + j) * N_DIM + col] = acc[mi][ni][j] + bv;
            }
        }
    }
}

// ---------- fallback (ws too small): fp32 LDS-tiled, correct but slow ----------
__global__ __launch_bounds__(256)
void gemm_fallback(const float* __restrict__ X, const float* __restrict__ W,
                   const float* __restrict__ scale, const float* __restrict__ bias,
                   float* __restrict__ C) {
    int bm = blockIdx.x % (M_DIM / 64);
    int bn = blockIdx.x / (M_DIM / 64);
    __shared__ float sA[64][33];
    __shared__ float sB[64][33];
    int t = threadIdx.x;
    int tx = t & 15, ty = t >> 4;
    float acc[4][4] = {};
    for (int kt = 0; kt < K_DIM / 32; ++kt) {
        float s = scale[(bn >> 1) * (K_DIM / 128) + (kt >> 2)];
        #pragma unroll
        for (int i = 0; i < 8; ++i) {
            int idx = t + i * 256;
            int r = idx >> 5, c = idx & 31;
            sA[r][c] = X[(size_t)(bm * 64 + r) * K_DIM + kt * 32 + c];
            sB[r][c] = W[(size_t)(bn * 64 + r) * K_DIM + kt * 32 + c] * s;
        }
        __syncthreads();
        #pragma unroll
        for (int k = 0; k < 32; ++k) {
            float a[4], b[4];
            #pragma unroll
            for (int i = 0; i < 4; ++i) a[i] = sA[ty * 4 + i][k];
            #pragma unroll
            for (int j = 0; j < 4; ++j) b[j] = sB[tx * 4 + j][k];
            #pragma unroll
            for (int i = 0; i < 4; ++i)
                #pragma unroll
                for (int j = 0; j < 4; ++j) acc[i][j] += a[i] * b[j];
        }
        __syncthreads();
    }
    #pragma unroll
    for (int i = 0; i < 4; ++i)
        #pragma unroll
        for (int j = 0; j < 4; ++j) {
            int row = bm * 64 + ty * 4 + i;
            int col = bn * 64 + tx * 4 + j;
            C[(size_t)row * N_DIM + col] = acc[i][j] + bias[col];
        }
}

extern "C" void kernel_launch(void* const* d_in, const int* in_sizes, int n_in,
                              void* d_out, int out_size, void* d_ws, size_t ws_size,
                              hipStream_t stream) {
    const float* x     = (const float*)d_in[0];   // [2,2048,4096]
    const float* wgt   = (const float*)d_in[1];   // [16384,4096]
    const float* scale = (const float*)d_in[2];   // [128,32]
    const float* bias  = (const float*)d_in[3];   // [16384]
    float* out = (float*)d_out;                   // [2,2048,16384]

    const size_t need = ((size_t)M_DIM * K_DIM + (size_t)N_DIM * K_DIM) * sizeof(__hip_bfloat16);
    if (ws_size >= need) {
        __hip_bfloat16* xbf = (__hip_bfloat16*)d_ws;
        __hip_bfloat16* wbf = xbf + (size_t)M_DIM * K_DIM;
        prep_kernel<<<6144, 256, 0, stream>>>(x, wgt, scale, xbf, wbf);
        gemm_bf16_kernel<<<(M_DIM / 256) * (N_DIM / 256), 256, 0, stream>>>(xbf, wbf, bias, out);
    } else {
        gemm_fallback<<<(M_DIM / 64) * (N_DIM / 64), 256, 0, stream>>>(x, wgt, scale, bias, out);
    }
}

// Round 19
// 765.575 us; speedup vs baseline: 5.5214x; 5.5214x over previous
//
#include <hip/hip_runtime.h>
#include <hip/hip_bf16.h>

// Problem: out[M=4096][N=16384] = x[M][K=4096] @ (W[N][K] * scale[N/128][K/128])^T + bias[N]
#define M_DIM 4096
#define N_DIM 16384
#define K_DIM 4096

typedef __bf16 bf16x8 __attribute__((ext_vector_type(8)));
typedef float f32x4 __attribute__((ext_vector_type(4)));

__device__ __forceinline__ void gload16(const void* g, void* l) {
    __builtin_amdgcn_global_load_lds((__attribute__((address_space(1))) void*)g,
                                     (__attribute__((address_space(3))) void*)l, 16, 0, 0);
}

// ---------- fused prepass: x fp32->bf16  +  W fp32*scale->bf16 (verified) ----
__global__ __launch_bounds__(256) void prep_kernel(const float* __restrict__ x,
                                                   const float* __restrict__ wgt,
                                                   const float* __restrict__ scale,
                                                   __hip_bfloat16* __restrict__ xbf,
                                                   __hip_bfloat16* __restrict__ wbf) {
    int b = blockIdx.x;
    if (b < 2048) {
        const int ng = M_DIM * K_DIM / 8;
        int i = b * 256 + threadIdx.x;
        for (; i < ng; i += 2048 * 256) {
            const float4* p = (const float4*)(x + (size_t)i * 8);
            float4 v0 = p[0];
            float4 v1 = p[1];
            bf16x8 r;
            r[0] = (__bf16)v0.x; r[1] = (__bf16)v0.y; r[2] = (__bf16)v0.z; r[3] = (__bf16)v0.w;
            r[4] = (__bf16)v1.x; r[5] = (__bf16)v1.y; r[6] = (__bf16)v1.z; r[7] = (__bf16)v1.w;
            *(bf16x8*)(xbf + (size_t)i * 8) = r;
        }
    } else {
        const int ng = N_DIM * (K_DIM / 8);
        int i = (b - 2048) * 256 + threadIdx.x;
        for (; i < ng; i += 4096 * 256) {
            int row = i >> 9;
            int cg  = i & 511;
            float s = scale[(row >> 7) * (K_DIM / 128) + (cg >> 4)];
            const float4* p = (const float4*)(wgt + (size_t)i * 8);
            float4 v0 = p[0];
            float4 v1 = p[1];
            bf16x8 r;
            r[0] = (__bf16)(v0.x * s); r[1] = (__bf16)(v0.y * s);
            r[2] = (__bf16)(v0.z * s); r[3] = (__bf16)(v0.w * s);
            r[4] = (__bf16)(v1.x * s); r[5] = (__bf16)(v1.y * s);
            r[6] = (__bf16)(v1.z * s); r[7] = (__bf16)(v1.w * s);
            *(bf16x8*)(wbf + (size_t)i * 8) = r;
        }
    }
}

// ---------- main GEMM: 256x128 tile, BK=32, 4 waves x 128x64, 2 blocks/CU ---
// r18 minus the spill: per-wave acc f32x4[8][4] = 128 VGPRs (total ~200,
// under the 256 cap at 2 waves/SIMD -> NO scratch). 48 KiB LDS -> 2
// independent blocks/CU whose barriers interleave (m97/m114 cross-block
// overlap) -- the one untested non-confounded mechanism left. Per-CU pipe
// totals per K=64 identical to r13 (512 MFMA / 192 b128), but split across
// two barrier groups. Free-zone schedule + 4-slot XOR swizzle verified
// correct by r18 (absmax 0.0625 under spill).
// LDS cell (r,s) holds k-octet s ^ ((r>>1)&3); reads balance 8 lanes per
// 16B bank-group (= b128 bandwidth balance; r13/r18 measured 0 conflicts).
// Stage (rule #21): linear LDS dest, pre-swizzled global col
// ((l&3)^((l>>3)&3))*8 (invariant across j,w: (r>>1)&3 == (l>>3)&3).
// Per K-step: vmcnt(6|0); BAR; [12 ds_read + 32 MFMA free zone]; lgkm0;
// BAR; stage(kt+2) = 4 A-gloads + 2 B-gloads per thread.
// vmcnt(6): queue = stage(kt)+stage(kt+1) (6 each, in-order) -> retires
// stage(kt) exactly.
template <int WN, bool ST>
__device__ __forceinline__ void ktile(const bf16x8* __restrict__ pa,
                                      const bf16x8* __restrict__ pb,
                                      char* lA, char* lB,
                                      const __hip_bfloat16* __restrict__ gA2,
                                      const __hip_bfloat16* __restrict__ gB2,
                                      f32x4 (&acc)[8][4],
                                      int arow, int brow, int srow) {
    const size_t K = K_DIM;
    if (WN == 0) asm volatile("s_waitcnt vmcnt(0)" ::: "memory");
    else         asm volatile("s_waitcnt vmcnt(6)" ::: "memory");
    __builtin_amdgcn_s_barrier();

    // free zone: compiler schedules reads <-> MFMAs
    bf16x8 a[8], b[4];
    #pragma unroll
    for (int mi = 0; mi < 8; ++mi)
        a[mi] = pa[arow + mi * 64];
    #pragma unroll
    for (int ni = 0; ni < 4; ++ni)
        b[ni] = pb[brow + ni * 64];
    __builtin_amdgcn_s_setprio(1);
    #pragma unroll
    for (int mi = 0; mi < 8; ++mi)
        #pragma unroll
        for (int ni = 0; ni < 4; ++ni)
            acc[mi][ni] = __builtin_amdgcn_mfma_f32_16x16x32_bf16(
                a[mi], b[ni], acc[mi][ni], 0, 0, 0);
    __builtin_amdgcn_s_setprio(0);

    asm volatile("s_waitcnt lgkmcnt(0)" ::: "memory");
    __builtin_amdgcn_s_barrier();
    if (ST) {
        #pragma unroll
        for (int j = 0; j < 4; ++j)
            gload16(gA2 + (size_t)(j * 64 + srow) * K, lA + j * 4096);
        #pragma unroll
        for (int j = 0; j < 2; ++j)
            gload16(gB2 + (size_t)(j * 64 + srow) * K, lB + j * 4096);
    }
}

__global__ __launch_bounds__(256, 2)
void gemm_bf16_kernel(const __hip_bfloat16* __restrict__ A,   // [M][K] bf16
                      const __hip_bfloat16* __restrict__ Bw,  // [N][K] bf16
                      const float* __restrict__ bias,
                      float* __restrict__ C) {                // [M][N] fp32
    constexpr int Mtiles = M_DIM / 256;            // 16
    constexpr int Ntiles = N_DIM / 128;            // 128
    constexpr int nwg = Mtiles * Ntiles;           // 2048 (div by 8)

    int bid = blockIdx.x;
    int swz = (bid & 7) * (nwg >> 3) + (bid >> 3);   // bijective XCD swizzle
    int bm = swz % Mtiles;
    int bn = swz / Mtiles;

    __shared__ bf16x8 sA[2][1024];   // 256 rows x 4 slots x 16B = 16 KiB each
    __shared__ bf16x8 sB[2][512];    // 128 rows x 4 slots x 16B =  8 KiB each
                                     // total 48 KiB -> 2 blocks/CU

    const int t = threadIdx.x;
    const int l = t & 63;
    const int w = t >> 6;        // wave 0..3
    const int wm = w >> 1;       // 0..1  (M half: 128 rows)
    const int wn = w & 1;        // 0..1  (N half: 64 cols)

    const int lr = l & 15;
    const int lk = l >> 4;       // k-octet 0..3
    const int sr = lk ^ ((lr >> 1) & 3);   // swizzled read slot

    // staging (rule #21): linear LDS dest, pre-swizzled global source col.
    const int srow = w * 16 + (l >> 2);            // + j*64 per gload
    const int scol = ((l & 3) ^ ((l >> 3) & 3)) << 3;

    const size_t K = K_DIM;
    const __hip_bfloat16* aB = A  + (size_t)(bm * 256) * K + scol;
    const __hip_bfloat16* bB = Bw + (size_t)(bn * 128) * K + scol;

    f32x4 acc[8][4] = {};

    const int arow = (wm * 128 + lr) * 4 + sr;   // + mi*64 slots
    const int brow = (wn * 64 + lr) * 4 + sr;    // + ni*64 slots

    char* A0b = (char*)&sA[0][0] + w * 1024;
    char* B0b = (char*)&sB[0][0] + w * 1024;
    char* A1b = (char*)&sA[1][0] + w * 1024;
    char* B1b = (char*)&sB[1][0] + w * 1024;
    const bf16x8* pa0 = &sA[0][0];
    const bf16x8* pb0 = &sB[0][0];
    const bf16x8* pa1 = &sA[1][0];
    const bf16x8* pb1 = &sB[1][0];

#define STAGE6(lA, lB, gA, gB)                                                  \
    do {                                                                        \
        _Pragma("unroll")                                                       \
        for (int j = 0; j < 4; ++j)                                             \
            gload16((gA) + (size_t)(j * 64 + srow) * K, (lA) + j * 4096);       \
        _Pragma("unroll")                                                       \
        for (int j = 0; j < 2; ++j)                                             \
            gload16((gB) + (size_t)(j * 64 + srow) * K, (lB) + j * 4096);       \
    } while (0)

    // prologue: stage step0 -> buf0, step1 -> buf1 (12 gloads in flight)
    STAGE6(A0b, B0b, aB, bB);
    STAGE6(A1b, B1b, aB + 32, bB + 32);

    #pragma unroll 1
    for (int p = 0; p < 63; ++p) {
        const int kt = 2 * p;
        ktile<6, true>(pa0, pb0, A0b, B0b,
                       aB + (size_t)(kt + 2) * 32, bB + (size_t)(kt + 2) * 32,
                       acc, arow, brow, srow);
        ktile<6, true>(pa1, pb1, A1b, B1b,
                       aB + (size_t)(kt + 3) * 32, bB + (size_t)(kt + 3) * 32,
                       acc, arow, brow, srow);
    }
    // steps 126, 127: no further staging
    ktile<6, false>(pa0, pb0, A0b, B0b, aB, bB, acc, arow, brow, srow);
    ktile<0, false>(pa1, pb1, A1b, B1b, aB, bB, acc, arow, brow, srow);
#undef STAGE6

    // epilogue: C/D layout col=lane&15, row=(lane>>4)*4+reg  [m89-verified]
    const int crow0 = bm * 256 + wm * 128;
    const int ccol0 = bn * 128 + wn * 64;
    #pragma unroll
    for (int ni = 0; ni < 4; ++ni) {
        int col = ccol0 + ni * 16 + lr;
        float bv = bias[col];
        #pragma unroll
        for (int mi = 0; mi < 8; ++mi) {
            int rbase = crow0 + mi * 16 + lk * 4;
            #pragma unroll
            for (int j = 0; j < 4; ++j) {
                C[(size_t)(rbase + j) * N_DIM + col] = acc[mi][ni][j] + bv;
            }
        }
    }
}

// ---------- fallback (ws too small): fp32 LDS-tiled, correct but slow ----------
__global__ __launch_bounds__(256)
void gemm_fallback(const float* __restrict__ X, const float* __restrict__ W,
                   const float* __restrict__ scale, const float* __restrict__ bias,
                   float* __restrict__ C) {
    int bm = blockIdx.x % (M_DIM / 64);
    int bn = blockIdx.x / (M_DIM / 64);
    __shared__ float sA[64][33];
    __shared__ float sB[64][33];
    int t = threadIdx.x;
    int tx = t & 15, ty = t >> 4;
    float acc[4][4] = {};
    for (int kt = 0; kt < K_DIM / 32; ++kt) {
        float s = scale[(bn >> 1) * (K_DIM / 128) + (kt >> 2)];
        #pragma unroll
        for (int i = 0; i < 8; ++i) {
            int idx = t + i * 256;
            int r = idx >> 5, c = idx & 31;
            sA[r][c] = X[(size_t)(bm * 64 + r) * K_DIM + kt * 32 + c];
            sB[r][c] = W[(size_t)(bn * 64 + r) * K_DIM + kt * 32 + c] * s;
        }
        __syncthreads();
        #pragma unroll
        for (int k = 0; k < 32; ++k) {
            float a[4], b[4];
            #pragma unroll
            for (int i = 0; i < 4; ++i) a[i] = sA[ty * 4 + i][k];
            #pragma unroll
            for (int j = 0; j < 4; ++j) b[j] = sB[tx * 4 + j][k];
            #pragma unroll
            for (int i = 0; i < 4; ++i)
                #pragma unroll
                for (int j = 0; j < 4; ++j) acc[i][j] += a[i] * b[j];
        }
        __syncthreads();
    }
    #pragma unroll
    for (int i = 0; i < 4; ++i)
        #pragma unroll
        for (int j = 0; j < 4; ++j) {
            int row = bm * 64 + ty * 4 + i;
            int col = bn * 64 + tx * 4 + j;
            C[(size_t)row * N_DIM + col] = acc[i][j] + bias[col];
        }
}

extern "C" void kernel_launch(void* const* d_in, const int* in_sizes, int n_in,
                              void* d_out, int out_size, void* d_ws, size_t ws_size,
                              hipStream_t stream) {
    const float* x     = (const float*)d_in[0];   // [2,2048,4096]
    const float* wgt   = (const float*)d_in[1];   // [16384,4096]
    const float* scale = (const float*)d_in[2];   // [128,32]
    const float* bias  = (const float*)d_in[3];   // [16384]
    float* out = (float*)d_out;                   // [2,2048,16384]

    const size_t need = ((size_t)M_DIM * K_DIM + (size_t)N_DIM * K_DIM) * sizeof(__hip_bfloat16);
    if (ws_size >= need) {
        __hip_bfloat16* xbf = (__hip_bfloat16*)d_ws;
        __hip_bfloat16* wbf = xbf + (size_t)M_DIM * K_DIM;
        prep_kernel<<<6144, 256, 0, stream>>>(x, wgt, scale, xbf, wbf);
        gemm_bf16_kernel<<<(M_DIM / 256) * (N_DIM / 128), 256, 0, stream>>>(xbf, wbf, bias, out);
    } else {
        gemm_fallback<<<(M_DIM / 64) * (N_DIM / 64), 256, 0, stream>>>(x, wgt, scale, bias, out);
    }
}